// Round 9
// baseline (289.172 us; speedup 1.0000x reference)
//
#include <hip/hip_runtime.h>
#include <stdint.h>

#define B_TOT 16384
#define F_NUM 24
#define P_NUM 276
#define BT    32          // b-rows per block (1 MFMA n-tile)
#define NTH   1024        // 16 waves -> 4 waves/SIMD
#define ROWP  1544        // shorts per LDS row: 24*64 + 8 pad

typedef float f32x16 __attribute__((ext_vector_type(16)));
typedef short bf16x8 __attribute__((ext_vector_type(8)));

__device__ inline unsigned short f2bf(float f) {
    unsigned u = __float_as_uint(f);
    u += 0x7fffu + ((u >> 16) & 1u);      // round-to-nearest-even
    return (unsigned short)(u >> 16);
}
__device__ inline float bf2f(unsigned short h) {
    return __uint_as_float(((unsigned)h) << 16);
}

// ---- pair schedule: 276 pairs (i-major) in 16 contiguous chunks ------------
// chunk sizes {18 x12, 15 x4} (all divisible by 3 for depth-3 rotation).
// epilogue flag at i-change or chunk end (partial epilogues exact: linearity).
// entry = p | (j<<9) | (i<<14) | (flag<<19)
struct Tab { int ent[16][18]; int cnt[16]; };
constexpr Tab build_tab() {
    Tab t{};
    int ii[276] = {}, jj[276] = {};
    int n = 0;
    for (int i = 0; i < 24; ++i)
        for (int j = i + 1; j < 24; ++j) { ii[n] = i; jj[n] = j; ++n; }
    int pos = 0;
    for (int w = 0; w < 16; ++w) {
        int c = (w < 12) ? 18 : 15;      // 12*18 + 4*15 = 276
        t.cnt[w] = c;
        for (int k = 0; k < c; ++k, ++pos) {
            int flag = (k == c - 1) || (ii[pos + 1] != ii[pos]);
            t.ent[w][k] = pos | (jj[pos] << 9) | (ii[pos] << 14) | (flag << 19);
        }
    }
    return t;
}
__device__ __constant__ Tab gtab = build_tab();

// ---- prepass: W fp32 -> bf16 A-fragments, pair-major chunk layout ----------
// chunk(p, u) u=ks*2+m at afrag[((p*8+u)*64 + lane)*8]:
//   elem i = W[p][m*32 + (lane&31)][ks*16 + (lane>>5)*8 + i]
__global__ __launch_bounds__(256) void wprep(const float* __restrict__ W,
                                             unsigned short* __restrict__ afrag) {
    __shared__ __align__(16) unsigned short wlds[64 * 72];
    int p = blockIdx.x, t = threadIdx.x;
    const float4* src = (const float4*)(W + (size_t)p * 4096);
    #pragma unroll
    for (int c = 0; c < 4; ++c) {
        int i = t + c * 256;
        float4 v = src[i];
        int d = i >> 4;
        int e = (i & 15) * 4;
        ushort4 h; h.x=f2bf(v.x); h.y=f2bf(v.y); h.z=f2bf(v.z); h.w=f2bf(v.w);
        *(ushort4*)(&wlds[d * 72 + e]) = h;
    }
    __syncthreads();
    #pragma unroll
    for (int c = 0; c < 2; ++c) {
        int sl = t + c * 256;
        int u = sl >> 6, lane = sl & 63;
        int ks = u >> 1, m = u & 1;
        int d = m * 32 + (lane & 31);
        int e = ks * 16 + (lane >> 5) * 8;
        bf16x8 v = *(const bf16x8*)(&wlds[d * 72 + e]);
        *(bf16x8*)(afrag + ((size_t)(p * 8 + u) * 64 + lane) * 8) = v;
    }
}

// ---- macros: named W buffers only (register-resident) ----------------------
#define LDA8(P_, A0,A1,A2,A3,A4,A5,A6,A7) do {                                 \
    const bf16x8* ap_ = afr + (size_t)(P_) * 512 + lane;                       \
    A0 = ap_[0];   A1 = ap_[64];  A2 = ap_[128]; A3 = ap_[192];                \
    A4 = ap_[256]; A5 = ap_[320]; A6 = ap_[384]; A7 = ap_[448]; } while (0)

// one pair: 4 b128 x-frag LDS reads, 8 MFMAs (2 m-chains), refill from pair
// NP_ = 3 pairs ahead (load->use ~3 pair-steps x 4-wave interleave)
#define STEP(E_, NP_, A0,A1,A2,A3,A4,A5,A6,A7) do {                            \
    int jb_ = ((E_ >> 9) & 31) * 64 + q8;                                      \
    const unsigned short* bp_ = xrow + jb_;                                    \
    bf16x8 bt0_ = *(const bf16x8*)(bp_);                                       \
    bf16x8 bt1_ = *(const bf16x8*)(bp_ + 16);                                  \
    bf16x8 bt2_ = *(const bf16x8*)(bp_ + 32);                                  \
    bf16x8 bt3_ = *(const bf16x8*)(bp_ + 48);                                  \
    a0 = __builtin_amdgcn_mfma_f32_32x32x16_bf16(A0, bt0_, a0, 0, 0, 0);       \
    a1 = __builtin_amdgcn_mfma_f32_32x32x16_bf16(A1, bt0_, a1, 0, 0, 0);       \
    a0 = __builtin_amdgcn_mfma_f32_32x32x16_bf16(A2, bt1_, a0, 0, 0, 0);       \
    a1 = __builtin_amdgcn_mfma_f32_32x32x16_bf16(A3, bt1_, a1, 0, 0, 0);       \
    a0 = __builtin_amdgcn_mfma_f32_32x32x16_bf16(A4, bt2_, a0, 0, 0, 0);       \
    a1 = __builtin_amdgcn_mfma_f32_32x32x16_bf16(A5, bt2_, a1, 0, 0, 0);       \
    a0 = __builtin_amdgcn_mfma_f32_32x32x16_bf16(A6, bt3_, a0, 0, 0, 0);       \
    a1 = __builtin_amdgcn_mfma_f32_32x32x16_bf16(A7, bt3_, a1, 0, 0, 0);       \
    LDA8(NP_, A0,A1,A2,A3,A4,A5,A6,A7);                                        \
    if (E_ & (1 << 19)) {                                                      \
        int fi_ = (E_ >> 14) & 31;                                             \
        const unsigned short* ep_ = xrow + fi_ * 64 + q4;                      \
        _Pragma("unroll")                                                      \
        for (int g = 0; g < 4; ++g) {                                          \
            ushort4 u0 = *(const ushort4*)(ep_ + 8 * g);                       \
            tacc += a0[4*g+0]*bf2f(u0.x) + a0[4*g+1]*bf2f(u0.y)                \
                  + a0[4*g+2]*bf2f(u0.z) + a0[4*g+3]*bf2f(u0.w);               \
            u0 = *(const ushort4*)(ep_ + 32 + 8 * g);                          \
            tacc += a1[4*g+0]*bf2f(u0.x) + a1[4*g+1]*bf2f(u0.y)                \
                  + a1[4*g+2]*bf2f(u0.z) + a1[4*g+3]*bf2f(u0.w);               \
        }                                                                      \
        _Pragma("unroll")                                                      \
        for (int k = 0; k < 16; ++k) { a0[k] = 0.f; a1[k] = 0.f; }             \
    } } while (0)

// ---- main kernel -----------------------------------------------------------
__global__ __launch_bounds__(NTH, 4) void fmfm_main(const float* __restrict__ x,
                                                    const unsigned short* __restrict__ afrag,
                                                    float* __restrict__ out) {
    __shared__ __align__(16) unsigned short xs[BT * ROWP];   // 98,816 B
    __shared__ float t_red[BT];
    const int tid = threadIdx.x;
    const int btile = blockIdx.x;
    const int lane = tid & 63;
    const int wv = __builtin_amdgcn_readfirstlane(tid >> 6);   // 0..15
    const int bcol = lane & 31;
    const int q = lane >> 5;
    const int q8 = q * 8, q4 = q * 4;

    if (tid < BT) t_red[tid] = 0.0f;

    const bf16x8* afr = (const bf16x8*)afrag;
    const unsigned short* xrow = xs + bcol * ROWP;

    float tacc = 0.f;
    f32x16 a0, a1;                        // acc[m]
    #pragma unroll
    for (int k = 0; k < 16; ++k) { a0[k] = 0.f; a1[k] = 0.f; }

    bf16x8 PA0,PA1,PA2,PA3,PA4,PA5,PA6,PA7;   // pair s
    bf16x8 PB0,PB1,PB2,PB3,PB4,PB5,PB6,PB7;   // pair s+1
    bf16x8 PC0,PC1,PC2,PC3,PC4,PC5,PC6,PC7;   // pair s+2

    const int cnt = gtab.cnt[wv];
    // prefetch first three pairs' W BEFORE staging: loads fly during the stage
    LDA8(gtab.ent[wv][0] & 511, PA0,PA1,PA2,PA3,PA4,PA5,PA6,PA7);
    LDA8(gtab.ent[wv][1] & 511, PB0,PB1,PB2,PB3,PB4,PB5,PB6,PB7);
    LDA8(gtab.ent[wv][2] & 511, PC0,PC1,PC2,PC3,PC4,PC5,PC6,PC7);

    // stage full tile: 32 rows x 6KB fp32 -> bf16 LDS, fully contiguous reads
    const float* xg = x + (size_t)btile * BT * 1536;
    #pragma unroll 4
    for (int c = 0; c < 12; ++c) {
        int idx = tid + c * NTH;         // 0..12287 float4 index
        int row = idx / 384;
        int c4  = idx - row * 384;
        float4 v = *(const float4*)(xg + (size_t)row * 1536 + c4 * 4);
        ushort4 h; h.x=f2bf(v.x); h.y=f2bf(v.y); h.z=f2bf(v.z); h.w=f2bf(v.w);
        *(ushort4*)(&xs[row * ROWP + c4 * 4]) = h;
    }
    __syncthreads();

    #pragma unroll 1
    for (int s = 0; s < cnt; s += 3) {   // cnt divisible by 3
        int e0 = gtab.ent[wv][s];
        int e1 = gtab.ent[wv][s + 1];
        int e2 = gtab.ent[wv][s + 2];
        int n0 = gtab.ent[wv][(s + 3 < cnt) ? s + 3 : cnt - 1] & 511;
        int n1 = gtab.ent[wv][(s + 4 < cnt) ? s + 4 : cnt - 1] & 511;
        int n2 = gtab.ent[wv][(s + 5 < cnt) ? s + 5 : cnt - 1] & 511;
        STEP(e0, n0, PA0,PA1,PA2,PA3,PA4,PA5,PA6,PA7);
        STEP(e1, n1, PB0,PB1,PB2,PB3,PB4,PB5,PB6,PB7);
        STEP(e2, n2, PC0,PC1,PC2,PC3,PC4,PC5,PC6,PC7);
    }

    atomicAdd(&t_red[bcol], tacc);
    __syncthreads();
    if (tid < BT) out[(size_t)btile * BT + tid] = t_red[tid];
}

extern "C" void kernel_launch(void* const* d_in, const int* in_sizes, int n_in,
                              void* d_out, int out_size, void* d_ws, size_t ws_size,
                              hipStream_t stream) {
    const float* x = (const float*)d_in[0];
    const float* W = (const float*)d_in[1];
    float* out = (float*)d_out;
    unsigned short* afrag = (unsigned short*)d_ws;   // 2.26 MB scratch
    wprep<<<P_NUM, 256, 0, stream>>>(W, afrag);
    fmfm_main<<<B_TOT / BT, NTH, 0, stream>>>(x, afrag, out);
}

// Round 10
// 196.278 us; speedup vs baseline: 1.4733x; 1.4733x over previous
//
#include <hip/hip_runtime.h>
#include <stdint.h>

#define B_TOT 16384
#define F_NUM 24
#define P_NUM 276
#define BT    32          // b-rows per block (1 MFMA n-tile)
#define NTH   512         // 8 waves -> 2 waves/SIMD (256-VGPR budget)
#define ROWP  1544        // shorts per LDS row: 24*64 + 8 pad

typedef float f32x16 __attribute__((ext_vector_type(16)));
typedef short bf16x8 __attribute__((ext_vector_type(8)));

__device__ inline unsigned short f2bf(float f) {
    unsigned u = __float_as_uint(f);
    u += 0x7fffu + ((u >> 16) & 1u);      // round-to-nearest-even
    return (unsigned short)(u >> 16);
}
__device__ inline float bf2f(unsigned short h) {
    return __uint_as_float(((unsigned)h) << 16);
}

// ---- per-wave schedule: contiguous i-major chunks, counts divisible by 4 ---
// chunk sizes {36,36,36,36,32,32,32,36}; (p0,i0,j0) = first pair of the chunk.
// Schedule advances incrementally in SALU (no per-step loads):
//   ++p; if (j==23) {++i; j=i+1;} else ++j;     epilogue at j==23 or chunk end.
struct WS { int p0, i0, j0, cnt; };
constexpr WS make_ws(int w) {
    const int cnts[8] = {36, 36, 36, 36, 32, 32, 32, 36};
    int s0 = 0;
    for (int k = 0; k < w; ++k) s0 += cnts[k];
    // invert i-major triangular index
    int i = 0, rem = s0;
    while (rem >= 23 - i) { rem -= 23 - i; ++i; }
    return WS{s0, i, i + 1 + rem, cnts[w]};
}
__device__ __constant__ WS gws[8] = {
    make_ws(0), make_ws(1), make_ws(2), make_ws(3),
    make_ws(4), make_ws(5), make_ws(6), make_ws(7)};

// ---- prepass: W fp32 -> bf16 A-fragments, pair-major chunk layout ----------
// chunk(p, u) u=ks*2+m at afrag[((p*8+u)*64 + lane)*8]:
//   elem i = W[p][m*32 + (lane&31)][ks*16 + (lane>>5)*8 + i]
__global__ __launch_bounds__(256) void wprep(const float* __restrict__ W,
                                             unsigned short* __restrict__ afrag) {
    __shared__ __align__(16) unsigned short wlds[64 * 72];
    int p = blockIdx.x, t = threadIdx.x;
    const float4* src = (const float4*)(W + (size_t)p * 4096);
    #pragma unroll
    for (int c = 0; c < 4; ++c) {
        int i = t + c * 256;
        float4 v = src[i];
        int d = i >> 4;
        int e = (i & 15) * 4;
        ushort4 h; h.x=f2bf(v.x); h.y=f2bf(v.y); h.z=f2bf(v.z); h.w=f2bf(v.w);
        *(ushort4*)(&wlds[d * 72 + e]) = h;
    }
    __syncthreads();
    #pragma unroll
    for (int c = 0; c < 2; ++c) {
        int sl = t + c * 256;
        int u = sl >> 6, lane = sl & 63;
        int ks = u >> 1, m = u & 1;
        int d = m * 32 + (lane & 31);
        int e = ks * 16 + (lane >> 5) * 8;
        bf16x8 v = *(const bf16x8*)(&wlds[d * 72 + e]);
        *(bf16x8*)(afrag + ((size_t)(p * 8 + u) * 64 + lane) * 8) = v;
    }
}

// ---- macros: named W buffers only (register-resident) ----------------------
#define LDA8(P_, A0,A1,A2,A3,A4,A5,A6,A7) do {                                 \
    const bf16x8* ap_ = afr + (size_t)(P_) * 512 + lane;                       \
    A0 = ap_[0];   A1 = ap_[64];  A2 = ap_[128]; A3 = ap_[192];                \
    A4 = ap_[256]; A5 = ap_[320]; A6 = ap_[384]; A7 = ap_[448]; } while (0)

// one pair: 4 b128 x-frag LDS reads, 8 MFMAs (2 m-chains), refill this buffer
// from pair p+4 (depth-4: load->use ~3 pair-steps x 2-wave interleave), then
// advance the scalar schedule and run the (wave-uniform) epilogue if flagged.
#define STEP(A0,A1,A2,A3,A4,A5,A6,A7) do {                                     \
    const unsigned short* bp_ = xrow + j * 64 + q8;                            \
    bf16x8 bt0_ = *(const bf16x8*)(bp_);                                       \
    bf16x8 bt1_ = *(const bf16x8*)(bp_ + 16);                                  \
    bf16x8 bt2_ = *(const bf16x8*)(bp_ + 32);                                  \
    bf16x8 bt3_ = *(const bf16x8*)(bp_ + 48);                                  \
    a0 = __builtin_amdgcn_mfma_f32_32x32x16_bf16(A0, bt0_, a0, 0, 0, 0);       \
    a1 = __builtin_amdgcn_mfma_f32_32x32x16_bf16(A1, bt0_, a1, 0, 0, 0);       \
    a0 = __builtin_amdgcn_mfma_f32_32x32x16_bf16(A2, bt1_, a0, 0, 0, 0);       \
    a1 = __builtin_amdgcn_mfma_f32_32x32x16_bf16(A3, bt1_, a1, 0, 0, 0);       \
    a0 = __builtin_amdgcn_mfma_f32_32x32x16_bf16(A4, bt2_, a0, 0, 0, 0);       \
    a1 = __builtin_amdgcn_mfma_f32_32x32x16_bf16(A5, bt2_, a1, 0, 0, 0);       \
    a0 = __builtin_amdgcn_mfma_f32_32x32x16_bf16(A6, bt3_, a0, 0, 0, 0);       \
    a1 = __builtin_amdgcn_mfma_f32_32x32x16_bf16(A7, bt3_, a1, 0, 0, 0);       \
    int np_ = p + 4; if (np_ >= pend) np_ = pend - 1;                          \
    LDA8(np_, A0,A1,A2,A3,A4,A5,A6,A7);                                        \
    if (j == 23 || p == pend - 1) {      /* wave-uniform epilogue */           \
        const unsigned short* ep_ = xrow + i * 64 + q4;                        \
        _Pragma("unroll")                                                      \
        for (int g_ = 0; g_ < 4; ++g_) {                                       \
            ushort4 u0 = *(const ushort4*)(ep_ + 8 * g_);                      \
            tacc += a0[4*g_+0]*bf2f(u0.x) + a0[4*g_+1]*bf2f(u0.y)              \
                  + a0[4*g_+2]*bf2f(u0.z) + a0[4*g_+3]*bf2f(u0.w);             \
            u0 = *(const ushort4*)(ep_ + 32 + 8 * g_);                         \
            tacc += a1[4*g_+0]*bf2f(u0.x) + a1[4*g_+1]*bf2f(u0.y)              \
                  + a1[4*g_+2]*bf2f(u0.z) + a1[4*g_+3]*bf2f(u0.w);             \
        }                                                                      \
        _Pragma("unroll")                                                      \
        for (int k_ = 0; k_ < 16; ++k_) { a0[k_] = 0.f; a1[k_] = 0.f; }        \
    }                                                                          \
    ++p;                                                                       \
    if (j == 23) { ++i; j = i + 1; } else { ++j; } } while (0)

// ---- main kernel -----------------------------------------------------------
__global__ __launch_bounds__(NTH, 2) void fmfm_main(const float* __restrict__ x,
                                                    const unsigned short* __restrict__ afrag,
                                                    float* __restrict__ out) {
    __shared__ __align__(16) unsigned short xs[BT * ROWP];   // 98,816 B
    __shared__ float t_red[BT];
    const int tid = threadIdx.x;
    const int btile = blockIdx.x;
    const int lane = tid & 63;
    const int wv = __builtin_amdgcn_readfirstlane(tid >> 6);   // 0..7
    const int bcol = lane & 31;
    const int q = lane >> 5;
    const int q8 = q * 8, q4 = q * 4;

    if (tid < BT) t_red[tid] = 0.0f;

    const bf16x8* afr = (const bf16x8*)afrag;
    const unsigned short* xrow = xs + bcol * ROWP;

    // scalar schedule state (SALU-resident, no per-step loads)
    WS ws = gws[wv];
    int p = ws.p0, i = ws.i0, j = ws.j0;
    const int pend = ws.p0 + ws.cnt;
    const int g4 = ws.cnt >> 2;

    float tacc = 0.f;
    f32x16 a0, a1;                        // acc[m]
    #pragma unroll
    for (int k = 0; k < 16; ++k) { a0[k] = 0.f; a1[k] = 0.f; }

    bf16x8 PA0,PA1,PA2,PA3,PA4,PA5,PA6,PA7;   // pair p
    bf16x8 PB0,PB1,PB2,PB3,PB4,PB5,PB6,PB7;   // pair p+1
    bf16x8 PC0,PC1,PC2,PC3,PC4,PC5,PC6,PC7;   // pair p+2
    bf16x8 PD0,PD1,PD2,PD3,PD4,PD5,PD6,PD7;   // pair p+3

    // prefetch first four pairs' W BEFORE staging: loads fly during the stage
    LDA8(p,     PA0,PA1,PA2,PA3,PA4,PA5,PA6,PA7);
    LDA8(p + 1, PB0,PB1,PB2,PB3,PB4,PB5,PB6,PB7);
    LDA8(p + 2, PC0,PC1,PC2,PC3,PC4,PC5,PC6,PC7);
    LDA8(p + 3, PD0,PD1,PD2,PD3,PD4,PD5,PD6,PD7);

    // stage full tile: 32 rows x 6KB fp32 -> bf16 LDS, fully contiguous reads
    const float* xg = x + (size_t)btile * BT * 1536;
    #pragma unroll 8
    for (int c = 0; c < 24; ++c) {
        int idx = tid + c * NTH;         // 0..12287 float4 index
        int row = idx / 384;
        int c4  = idx - row * 384;
        float4 v = *(const float4*)(xg + (size_t)row * 1536 + c4 * 4);
        ushort4 h; h.x=f2bf(v.x); h.y=f2bf(v.y); h.z=f2bf(v.z); h.w=f2bf(v.w);
        *(ushort4*)(&xs[row * ROWP + c4 * 4]) = h;
    }
    __syncthreads();

    #pragma unroll 1
    for (int g = 0; g < g4; ++g) {       // 4 pair-steps per iteration
        STEP(PA0,PA1,PA2,PA3,PA4,PA5,PA6,PA7);
        STEP(PB0,PB1,PB2,PB3,PB4,PB5,PB6,PB7);
        STEP(PC0,PC1,PC2,PC3,PC4,PC5,PC6,PC7);
        STEP(PD0,PD1,PD2,PD3,PD4,PD5,PD6,PD7);
    }

    atomicAdd(&t_red[bcol], tacc);
    __syncthreads();
    if (tid < BT) out[(size_t)btile * BT + tid] = t_red[tid];
}

extern "C" void kernel_launch(void* const* d_in, const int* in_sizes, int n_in,
                              void* d_out, int out_size, void* d_ws, size_t ws_size,
                              hipStream_t stream) {
    const float* x = (const float*)d_in[0];
    const float* W = (const float*)d_in[1];
    float* out = (float*)d_out;
    unsigned short* afrag = (unsigned short*)d_ws;   // 2.26 MB scratch
    wprep<<<P_NUM, 256, 0, stream>>>(W, afrag);
    fmfm_main<<<B_TOT / BT, NTH, 0, stream>>>(x, afrag, out);
}